// Round 14
// baseline (5879.358 us; speedup 1.0000x reference)
//
#include <hip/hip_runtime.h>
#include <hip/hip_bf16.h>

// GRU: SEQ=512, B=64, I=512, H=1024, O=512
#define SEQL 512
#define BATCH 64
#define INF 512
#define HID 1024
#define OUTF 512
#define SB (SEQL*BATCH)
#define BH (BATCH*HID)

typedef __attribute__((ext_vector_type(8))) __bf16 bf16x8;
typedef __attribute__((ext_vector_type(4))) float f32x4;

__device__ inline bf16x8 ld_bf8(const void* p) { return *reinterpret_cast<const bf16x8*>(p); }
__device__ inline unsigned short f2bf(float f) { __bf16 b = (__bf16)f; return __builtin_bit_cast(unsigned short, b); }

// Coherent 8B store: relaxed agent-scope atomic -> write-through to IF, no cache maintenance.
__device__ inline void st_u64c(void* p, unsigned long long v) {
    __hip_atomic_store((unsigned long long*)p, v, __ATOMIC_RELAXED, __HIP_MEMORY_SCOPE_AGENT);
}

// ---------------- prep kernels ----------------
__global__ void cvt_f32_bf16(const float* __restrict__ src, unsigned short* __restrict__ dst, int n) {
    int i = (blockIdx.x * blockDim.x + threadIdx.x) * 4;
    if (i < n) {
        float4 v = *reinterpret_cast<const float4*>(src + i);
        ushort4 o = make_ushort4(f2bf(v.x), f2bf(v.y), f2bf(v.z), f2bf(v.w));
        *reinterpret_cast<ushort4*>(dst + i) = o;
    }
}

__global__ void make_bias2(const float* bxz, const float* bhz, const float* bxr,
                           const float* bhr, float* bias2) {
    int i = blockIdx.x * blockDim.x + threadIdx.x;
    if (i < HID) bias2[i] = bxz[i] + bhz[i];
    else if (i < 2*HID) bias2[i] = bxr[i-HID] + bhr[i-HID];
}

__global__ void fail_sentinel(float* o) { o[0] = 1e9f; }

// ---------------- tiled NT GEMM (unchanged, validated) ----------------
__global__ __launch_bounds__(256, 2) void gemm_nt_f32(
        const unsigned short* __restrict__ A, int lda,
        const unsigned short* __restrict__ Bw, int ldb,
        const float* __restrict__ bias,
        float* __restrict__ Cf, int N, int K) {
    __shared__ __align__(16) char lds[32768];
    const int tid = threadIdx.x;
    const int ntn = N >> 7;
    const int bm = blockIdx.x / ntn, bn = blockIdx.x % ntn;
    const int rowbase = bm << 7, colbase = bn << 7;
    const int wave = tid >> 6, lane = tid & 63, lo = lane & 15, hi = lane >> 4;
    const int vm = wave >> 1, vn = wave & 1;

    auto stage = [&](int abase, int k0) {
        #pragma unroll
        for (int i = 0; i < 2; i++) {
            int linear = i * 256 + tid;
            int r = linear >> 2, s = linear & 3;
            int c = (s - (r >> 1)) & 3;
            const unsigned short* ga = A + (size_t)(rowbase + r) * lda + k0 + c * 8;
            const unsigned short* gb = Bw + (size_t)(colbase + r) * ldb + k0 + c * 8;
            __builtin_amdgcn_global_load_lds(
                (const __attribute__((address_space(1))) unsigned int*)ga,
                (__attribute__((address_space(3))) unsigned int*)(lds + abase + linear * 16), 16, 0, 0);
            __builtin_amdgcn_global_load_lds(
                (const __attribute__((address_space(1))) unsigned int*)gb,
                (__attribute__((address_space(3))) unsigned int*)(lds + 16384 + abase + linear * 16), 16, 0, 0);
        }
    };

    f32x4 acc[4][4] = {};
    const int nk = K >> 5;
    stage(0, 0);
    for (int kt = 0; kt < nk; kt++) {
        __syncthreads();
        if (kt + 1 < nk) stage(((kt + 1) & 1) * 8192, (kt + 1) << 5);
        const char* cA = lds + (kt & 1) * 8192;
        const char* cB = lds + 16384 + (kt & 1) * 8192;
        bf16x8 af[4], bfr[4];
        #pragma unroll
        for (int m = 0; m < 4; m++) {
            int r = vm * 64 + m * 16 + lo;
            af[m] = ld_bf8(cA + r * 64 + 16 * ((hi + (r >> 1)) & 3));
        }
        #pragma unroll
        for (int n = 0; n < 4; n++) {
            int r = vn * 64 + n * 16 + lo;
            bfr[n] = ld_bf8(cB + r * 64 + 16 * ((hi + (r >> 1)) & 3));
        }
        #pragma unroll
        for (int m = 0; m < 4; m++)
            #pragma unroll
            for (int n = 0; n < 4; n++)
                acc[m][n] = __builtin_amdgcn_mfma_f32_16x16x32_bf16(af[m], bfr[n], acc[m][n], 0, 0, 0);
        __syncthreads();
    }

    #pragma unroll
    for (int n = 0; n < 4; n++) {
        int col = colbase + vn * 64 + n * 16 + lo;
        float bv = bias[col];
        #pragma unroll
        for (int m = 0; m < 4; m++)
            #pragma unroll
            for (int r = 0; r < 4; r++) {
                int row = rowbase + vm * 64 + m * 16 + hi * 4 + r;
                Cf[(size_t)row * N + col] = acc[m][n][r] + bv;
            }
    }
}

// ---------------- persistent GRU scan v10: DUAL-PIPELINE (two interleaved sub-scans) ----------------
// 128 WGs x 192 threads; p = wid>>6 (pair 0..1), cb = wid&63 (16 h-cols); wave g = gate.
// WG p runs TWO independent 16-row sub-scans: A = rows 32p..32p+15, B = rows 32p+16..32p+31,
// interleaved so each scan's sync RTTs (poll, stage landing, producer drain) hide under the
// OTHER scan's MFMA/finalize work. Weights are SHARED (same 16 cols) -> wh LDS unchanged.
// LDS (exactly 160KB): [0,96K) wh; [96K,128K) tileA; [128K,160K) tileB. Px (3KB) and T (512B)
// ALIAS the head of each tile -- tile bytes are dead between consume(t) and stage(t+1),
// barrier-proven: PxA written after B1 (consume-A done), read by wave0 after B2, tile-A
// restaged only after B3. h tiles keep r8/r11's fragment-major layout (~0 bank conflicts).
// Barrier schedule per iteration (2 logical steps' worth of sync, 4 barriers):
//   consume-A | B1 | PxA-write + consume-B | B2 | wave0: finalize-A / w12: PxB-write | B3
//   (implicit vmcnt(0) at B3 drains hA stores -> flagA is FREE) | wave0: flagA+finalize-B+xprefA
//   / w12: xprefA + pollA + stageA(t+1) + xprefB | B4 | wave0: flagB+xprefB / w12: pollB+stageB(t+1)
// Producer: T-repack -> one 8B agent-scope store/lane; flags are plain stores (no RMW).
// Cached stage loads (r11-validated; startup buffer_inv kills pre-launch L2 lines).
__global__ __launch_bounds__(192, 1) void gru_scan(
        const unsigned short* __restrict__ Whc,   // [3][H][H]
        const unsigned short* __restrict__ Wxc,   // [3][H][I]
        const unsigned short* __restrict__ xbf,   // [S*B][I]
        unsigned short* __restrict__ hs,          // [S+1][B][H]
        const float* __restrict__ bias2,          // [2H]
        const float* __restrict__ bxh,
        const float* __restrict__ bhh,
        unsigned int* flags) {                    // [2 pairs][2 subs][64]
    __shared__ __align__(16) char lds[163840];
    const int tid = threadIdx.x;
    const int wid = blockIdx.x;       // 0..127
    const int p  = wid >> 6;          // pair
    const int cb = wid & 63;
    const int g = tid / 64;
    const int lane = tid & 63, lo = lane & 15, hi = lane >> 4;
    const int col = cb * 16 + lo;
    char* whl  = lds + g * 32768;
    char* tileA = lds + 98304;
    char* tileB = lds + 131072;
    f32x4* PxA = (f32x4*)(tileA + 512);     // [0..63]=r-pre [64..127]=h-part [128..191]=x-part
    f32x4* PxB = (f32x4*)(tileB + 512);
    unsigned short* TA = (unsigned short*)tileA;   // 512B repack
    unsigned short* TB = (unsigned short*)tileB;
    const int rowA = p * 32, rowB = p * 32 + 16;

    // ---- stage wh slices into LDS (once) ----
    {
        const unsigned short* ph = Whc + ((size_t)g * HID + col) * HID + hi * 8;
        #pragma unroll
        for (int kb = 0; kb < 32; kb++)
            __builtin_amdgcn_global_load_lds(
                (const __attribute__((address_space(1))) unsigned int*)(ph + kb * 32),
                (__attribute__((address_space(3))) unsigned int*)(whl + kb * 1024 + lane * 16), 16, 0, 0);
    }
    __syncthreads();
    asm volatile("buffer_inv sc0 sc1" ::: "memory");   // kill pre-launch hsbuf L2 lines

    const float bzv  = bias2[col];
    const float brv  = bias2[HID + col];
    const float bxhv = bxh[col];
    const float bhhv = bhh[col];
    float hstA[4] = {0.f,0.f,0.f,0.f}, hstB[4] = {0.f,0.f,0.f,0.f};
    const unsigned short* wxp = Wxc + ((size_t)g * HID + col) * INF + hi * 8;
    unsigned int* flagA = flags + p * 128 + cb;
    unsigned int* flagB = flags + p * 128 + 64 + cb;
    const unsigned int* pfA = flags + p * 128 + lane;
    const unsigned int* pfB = flags + p * 128 + 64 + lane;
    const int sidx = tid - 64;        // stage index for waves 1,2 (0..127)

    // x-side preacts for t=0 (both sub-scans)
    f32x4 axA = {0,0,0,0}, axB = {0,0,0,0};
    {
        const unsigned short* xpA = xbf + (size_t)(rowA + lo) * INF + hi * 8;
        const unsigned short* xpB = xbf + (size_t)(rowB + lo) * INF + hi * 8;
        #pragma unroll
        for (int kb = 0; kb < 16; kb++) {
            bf16x8 w = ld_bf8(wxp + kb * 32);
            axA = __builtin_amdgcn_mfma_f32_16x16x32_bf16(ld_bf8(xpA + kb * 32), w, axA, 0, 0, 0);
            axB = __builtin_amdgcn_mfma_f32_16x16x32_bf16(ld_bf8(xpB + kb * 32), w, axB, 0, 0, 0);
        }
    }

    for (int t = 0; t < SEQL; t++) {
        // --- consume-A (tile-A(t) landed at prev B4) ---
        f32x4 ahA = {0,0,0,0}, ahB = {0,0,0,0};
        if (t > 0) {
            #pragma unroll
            for (int kb = 0; kb < 32; kb++) {
                bf16x8 w = ld_bf8(whl + kb * 1024 + lane * 16);
                bf16x8 a = ld_bf8(tileA + kb * 1024 + lane * 16);
                ahA = __builtin_amdgcn_mfma_f32_16x16x32_bf16(a, w, ahA, 0, 0, 0);
            }
        }
        __syncthreads();   // B1: consume-A done; tile-B(t) landed

        if (g == 1) {
            f32x4 v;
            #pragma unroll
            for (int r = 0; r < 4; r++) v[r] = ahA[r] + axA[r] + brv;
            PxA[lane] = v;
        } else if (g == 2) {
            f32x4 v, w2;
            #pragma unroll
            for (int r = 0; r < 4; r++) { v[r] = ahA[r] + bhhv; w2[r] = axA[r] + bxhv; }
            PxA[64 + lane] = v; PxA[128 + lane] = w2;
        }
        if (t > 0) {
            #pragma unroll
            for (int kb = 0; kb < 32; kb++) {
                bf16x8 w = ld_bf8(whl + kb * 1024 + lane * 16);
                bf16x8 a = ld_bf8(tileB + kb * 1024 + lane * 16);
                ahB = __builtin_amdgcn_mfma_f32_16x16x32_bf16(a, w, ahB, 0, 0, 0);
            }
        }
        __syncthreads();   // B2: PxA visible; consume-B done

        if (g == 0) {      // finalize-A
            unsigned short* hdst = hs + (size_t)(t + 1) * BH;
            f32x4 pr = PxA[lane], ph_ = PxA[64 + lane], px_ = PxA[128 + lane];
            #pragma unroll
            for (int r = 0; r < 4; r++) {
                float z  = 1.f / (1.f + __expf(-(ahA[r] + axA[r] + bzv)));
                float rr = 1.f / (1.f + __expf(-pr[r]));
                float hc = tanhf(px_[r] + rr * ph_[r]);
                hstA[r] = (1.f - z) * hstA[r] + z * hc;
                TA[(hi * 4 + r) * 16 + lo] = f2bf(hstA[r]);
            }
            asm volatile("s_waitcnt lgkmcnt(0)" ::: "memory");
            int row = lane >> 2, q = lane & 3;
            st_u64c(hdst + (size_t)(rowA + row) * HID + cb * 16 + q * 4,
                    *(const unsigned long long*)(TA + row * 16 + q * 4));
        } else if (g == 1) {
            f32x4 v;
            #pragma unroll
            for (int r = 0; r < 4; r++) v[r] = ahB[r] + axB[r] + brv;
            PxB[lane] = v;
        } else {
            f32x4 v, w2;
            #pragma unroll
            for (int r = 0; r < 4; r++) { v[r] = ahB[r] + bhhv; w2[r] = axB[r] + bxhv; }
            PxB[64 + lane] = v; PxB[128 + lane] = w2;
        }
        __syncthreads();   // B3: implicit vmcnt(0) drained hA stores; PxB visible; tile-A free

        f32x4 naxA = {0,0,0,0}, naxB = {0,0,0,0};
        if (g == 0) {
            if (tid == 0)
                __hip_atomic_store(flagA, (unsigned int)(t + 1), __ATOMIC_RELAXED, __HIP_MEMORY_SCOPE_AGENT);
            // finalize-B
            unsigned short* hdst = hs + (size_t)(t + 1) * BH;
            f32x4 pr = PxB[lane], ph_ = PxB[64 + lane], px_ = PxB[128 + lane];
            #pragma unroll
            for (int r = 0; r < 4; r++) {
                float z  = 1.f / (1.f + __expf(-(ahB[r] + axB[r] + bzv)));
                float rr = 1.f / (1.f + __expf(-pr[r]));
                float hc = tanhf(px_[r] + rr * ph_[r]);
                hstB[r] = (1.f - z) * hstB[r] + z * hc;
                TB[(hi * 4 + r) * 16 + lo] = f2bf(hstB[r]);
            }
            asm volatile("s_waitcnt lgkmcnt(0)" ::: "memory");
            int row = lane >> 2, q = lane & 3;
            st_u64c(hdst + (size_t)(rowB + row) * HID + cb * 16 + q * 4,
                    *(const unsigned long long*)(TB + row * 16 + q * 4));
            if (t + 1 < SEQL) {   // wave0 x-prefetch A
                const unsigned short* xpA = xbf + ((size_t)(t + 1) * BATCH + rowA + lo) * INF + hi * 8;
                #pragma unroll
                for (int kb = 0; kb < 16; kb++)
                    naxA = __builtin_amdgcn_mfma_f32_16x16x32_bf16(ld_bf8(xpA + kb * 32), ld_bf8(wxp + kb * 32), naxA, 0, 0, 0);
            }
        } else if (t + 1 < SEQL) {
            {   // waves 1,2: x-prefetch A, then poll+stage A(t+1)
                const unsigned short* xpA = xbf + ((size_t)(t + 1) * BATCH + rowA + lo) * INF + hi * 8;
                #pragma unroll
                for (int kb = 0; kb < 16; kb++)
                    naxA = __builtin_amdgcn_mfma_f32_16x16x32_bf16(ld_bf8(xpA + kb * 32), ld_bf8(wxp + kb * 32), naxA, 0, 0, 0);
            }
            {
                unsigned int tgt = (unsigned int)(t + 1);
                while (!__all(__hip_atomic_load(pfA, __ATOMIC_RELAXED, __HIP_MEMORY_SCOPE_AGENT) >= tgt))
                    __builtin_amdgcn_s_sleep(1);
                asm volatile("" ::: "memory");
            }
            {
                const unsigned short* hsrc = hs + (size_t)(t + 1) * BH + (size_t)rowA * HID;
                #pragma unroll
                for (int it = 0; it < 16; it++) {
                    int u = it * 128 + sidx;
                    __builtin_amdgcn_global_load_lds(
                        (const __attribute__((address_space(1))) unsigned int*)(hsrc + (size_t)(u & 15) * HID + (u >> 4) * 8),
                        (__attribute__((address_space(3))) unsigned int*)(tileA + u * 16), 16, 0, 0);
                }
            }
            {   // x-prefetch B
                const unsigned short* xpB = xbf + ((size_t)(t + 1) * BATCH + rowB + lo) * INF + hi * 8;
                #pragma unroll
                for (int kb = 0; kb < 16; kb++)
                    naxB = __builtin_amdgcn_mfma_f32_16x16x32_bf16(ld_bf8(xpB + kb * 32), ld_bf8(wxp + kb * 32), naxB, 0, 0, 0);
            }
        }
        __syncthreads();   // B4: tile-A(t+1) landed; hB stores drained; finalize-B LDS reads done -> tile-B free

        if (g == 0) {
            if (tid == 0)
                __hip_atomic_store(flagB, (unsigned int)(t + 1), __ATOMIC_RELAXED, __HIP_MEMORY_SCOPE_AGENT);
            if (t + 1 < SEQL) {   // wave0 x-prefetch B
                const unsigned short* xpB = xbf + ((size_t)(t + 1) * BATCH + rowB + lo) * INF + hi * 8;
                #pragma unroll
                for (int kb = 0; kb < 16; kb++)
                    naxB = __builtin_amdgcn_mfma_f32_16x16x32_bf16(ld_bf8(xpB + kb * 32), ld_bf8(wxp + kb * 32), naxB, 0, 0, 0);
            }
        } else if (t + 1 < SEQL) {
            unsigned int tgt = (unsigned int)(t + 1);
            while (!__all(__hip_atomic_load(pfB, __ATOMIC_RELAXED, __HIP_MEMORY_SCOPE_AGENT) >= tgt))
                __builtin_amdgcn_s_sleep(1);
            asm volatile("" ::: "memory");
            const unsigned short* hsrc = hs + (size_t)(t + 1) * BH + (size_t)rowB * HID;
            #pragma unroll
            for (int it = 0; it < 16; it++) {
                int u = it * 128 + sidx;
                __builtin_amdgcn_global_load_lds(
                    (const __attribute__((address_space(1))) unsigned int*)(hsrc + (size_t)(u & 15) * HID + (u >> 4) * 8),
                    (__attribute__((address_space(3))) unsigned int*)(tileB + u * 16), 16, 0, 0);
            }
        }
        axA = naxA; axB = naxB;
    }
}

// ---------------- host ----------------
extern "C" void kernel_launch(void* const* d_in, const int* in_sizes, int n_in,
                              void* d_out, int out_size, void* d_ws, size_t ws_size,
                              hipStream_t stream) {
    const float* x   = (const float*)d_in[0];
    const float* Wxz = (const float*)d_in[1];
    const float* bxz = (const float*)d_in[2];
    const float* Whz = (const float*)d_in[3];
    const float* bhz = (const float*)d_in[4];
    const float* Wxr = (const float*)d_in[5];
    const float* bxr = (const float*)d_in[6];
    const float* Whr = (const float*)d_in[7];
    const float* bhr = (const float*)d_in[8];
    const float* Wxh = (const float*)d_in[9];
    const float* bxh = (const float*)d_in[10];
    const float* Whh = (const float*)d_in[11];
    const float* bhh = (const float*)d_in[12];
    const float* Why = (const float*)d_in[13];
    const float* bhy = (const float*)d_in[14];

    char* ws = (char*)d_ws;
    size_t off = 0;
    auto alloc = [&](size_t bytes) { char* p = ws + off; off += (bytes + 255) & ~(size_t)255; return p; };
    unsigned short* Whc   = (unsigned short*)alloc((size_t)3 * HID * HID * 2);
    unsigned short* Wxc   = (unsigned short*)alloc((size_t)3 * HID * INF * 2);
    unsigned short* Whyb  = (unsigned short*)alloc((size_t)OUTF * HID * 2);
    float*          bias2 = (float*)alloc((size_t)2 * HID * 4);
    unsigned short* hsbuf = (unsigned short*)alloc((size_t)(SEQL + 1) * BATCH * HID * 2);
    unsigned int*   flags = (unsigned int*)alloc(1024);
    unsigned short* x_bf  = (unsigned short*)d_out;  // dead until the final GEMM

    if (off > ws_size) {
        fail_sentinel<<<dim3(1), dim3(1), 0, stream>>>((float*)d_out);
        return;
    }

    auto cvt = [&](const float* s, unsigned short* d, size_t n) {
        cvt_f32_bf16<<<dim3((unsigned)((n / 4 + 255) / 256)), dim3(256), 0, stream>>>(s, d, (int)n);
    };
    cvt(x, x_bf, (size_t)SB * INF);
    cvt(Whz, Whc, (size_t)HID * HID);
    cvt(Whr, Whc + (size_t)HID * HID, (size_t)HID * HID);
    cvt(Whh, Whc + (size_t)2 * HID * HID, (size_t)HID * HID);
    cvt(Wxz, Wxc, (size_t)HID * INF);
    cvt(Wxr, Wxc + (size_t)HID * INF, (size_t)HID * INF);
    cvt(Wxh, Wxc + (size_t)2 * HID * INF, (size_t)HID * INF);
    cvt(Why, Whyb, (size_t)OUTF * HID);
    make_bias2<<<dim3(8), dim3(256), 0, stream>>>(bxz, bhz, bxr, bhr, bias2);
    (void)hipMemsetAsync(flags, 0, 1024, stream);   // reset per launch (graph-replay safe)

    gru_scan<<<dim3(128), dim3(192), 0, stream>>>(Whc, Wxc, x_bf, hsbuf, bias2, bxh, bhh, flags);

    gemm_nt_f32<<<dim3((SB / 128) * (OUTF / 128)), dim3(256), 0, stream>>>(
        hsbuf + (size_t)BATCH * HID, HID, Whyb, HID, bhy, (float*)d_out, OUTF, HID);
}

// Round 15
// 2856.872 us; speedup vs baseline: 2.0580x; 2.0580x over previous
//
#include <hip/hip_runtime.h>
#include <hip/hip_bf16.h>

// GRU: SEQ=512, B=64, I=512, H=1024, O=512
#define SEQL 512
#define BATCH 64
#define INF 512
#define HID 1024
#define OUTF 512
#define SB (SEQL*BATCH)
#define BH (BATCH*HID)

typedef __attribute__((ext_vector_type(8))) __bf16 bf16x8;
typedef __attribute__((ext_vector_type(4))) float f32x4;

__device__ inline bf16x8 ld_bf8(const void* p) { return *reinterpret_cast<const bf16x8*>(p); }
__device__ inline unsigned short f2bf(float f) { __bf16 b = (__bf16)f; return __builtin_bit_cast(unsigned short, b); }

// Coherent 8B store: relaxed agent-scope atomic -> write-through to IF, no cache maintenance.
__device__ inline void st_u64c(void* p, unsigned long long v) {
    __hip_atomic_store((unsigned long long*)p, v, __ATOMIC_RELAXED, __HIP_MEMORY_SCOPE_AGENT);
}

// ---------------- prep kernels ----------------
__global__ void cvt_f32_bf16(const float* __restrict__ src, unsigned short* __restrict__ dst, int n) {
    int i = (blockIdx.x * blockDim.x + threadIdx.x) * 4;
    if (i < n) {
        float4 v = *reinterpret_cast<const float4*>(src + i);
        ushort4 o = make_ushort4(f2bf(v.x), f2bf(v.y), f2bf(v.z), f2bf(v.w));
        *reinterpret_cast<ushort4*>(dst + i) = o;
    }
}

__global__ void make_bias2(const float* bxz, const float* bhz, const float* bxr,
                           const float* bhr, float* bias2) {
    int i = blockIdx.x * blockDim.x + threadIdx.x;
    if (i < HID) bias2[i] = bxz[i] + bhz[i];
    else if (i < 2*HID) bias2[i] = bxr[i-HID] + bhr[i-HID];
}

__global__ void fail_sentinel(float* o) { o[0] = 1e9f; }

// ---------------- tiled NT GEMM; A is read from the FRAGMENT-MAJOR hs layout ----------------
// hsFM layout: t-block = 128KB (65536 ushorts) = 4 rb-blocks x 2048 units x 16B;
// unit v = slot*16 + row16 holds h[t][rb*16+row16][slot*8 .. slot*8+7].
// A-fragment (R, k..k+7) -> A + (R>>6)*65536 + ((R>>4)&3)*16384 + (((k>>3)*16 + (R&15))*8).
// Per wave the 64 lanes hit 4 slots x (16 rows x 16B contiguous) = 256B blocks: coalesced.
__global__ __launch_bounds__(256, 2) void gemm_nt_f32(
        const unsigned short* __restrict__ A,     // hsFM + one t-block (t=1 start)
        const unsigned short* __restrict__ Bw, int ldb,
        const float* __restrict__ bias,
        float* __restrict__ Cf, int N, int K) {
    __shared__ __align__(16) char lds[32768];
    const int tid = threadIdx.x;
    const int ntn = N >> 7;
    const int bm = blockIdx.x / ntn, bn = blockIdx.x % ntn;
    const int rowbase = bm << 7, colbase = bn << 7;
    const int wave = tid >> 6, lane = tid & 63, lo = lane & 15, hi = lane >> 4;
    const int vm = wave >> 1, vn = wave & 1;

    auto stage = [&](int abase, int k0) {
        #pragma unroll
        for (int i = 0; i < 2; i++) {
            int linear = i * 256 + tid;
            int r = linear >> 2, s = linear & 3;
            int c = (s - (r >> 1)) & 3;
            int R = rowbase + r;
            const unsigned short* ga = A + ((size_t)(R >> 6) * 65536 + (size_t)((R >> 4) & 3) * 16384
                                     + (size_t)((((k0 + c * 8) >> 3) * 16) + (R & 15)) * 8);
            const unsigned short* gb = Bw + (size_t)(colbase + r) * ldb + k0 + c * 8;
            __builtin_amdgcn_global_load_lds(
                (const __attribute__((address_space(1))) unsigned int*)ga,
                (__attribute__((address_space(3))) unsigned int*)(lds + abase + linear * 16), 16, 0, 0);
            __builtin_amdgcn_global_load_lds(
                (const __attribute__((address_space(1))) unsigned int*)gb,
                (__attribute__((address_space(3))) unsigned int*)(lds + 16384 + abase + linear * 16), 16, 0, 0);
        }
    };

    f32x4 acc[4][4] = {};
    const int nk = K >> 5;
    stage(0, 0);
    for (int kt = 0; kt < nk; kt++) {
        __syncthreads();
        if (kt + 1 < nk) stage(((kt + 1) & 1) * 8192, (kt + 1) << 5);
        const char* cA = lds + (kt & 1) * 8192;
        const char* cB = lds + 16384 + (kt & 1) * 8192;
        bf16x8 af[4], bfr[4];
        #pragma unroll
        for (int m = 0; m < 4; m++) {
            int r = vm * 64 + m * 16 + lo;
            af[m] = ld_bf8(cA + r * 64 + 16 * ((hi + (r >> 1)) & 3));
        }
        #pragma unroll
        for (int n = 0; n < 4; n++) {
            int r = vn * 64 + n * 16 + lo;
            bfr[n] = ld_bf8(cB + r * 64 + 16 * ((hi + (r >> 1)) & 3));
        }
        #pragma unroll
        for (int m = 0; m < 4; m++)
            #pragma unroll
            for (int n = 0; n < 4; n++)
                acc[m][n] = __builtin_amdgcn_mfma_f32_16x16x32_bf16(af[m], bfr[n], acc[m][n], 0, 0, 0);
        __syncthreads();
    }

    #pragma unroll
    for (int n = 0; n < 4; n++) {
        int col = colbase + vn * 64 + n * 16 + lo;
        float bv = bias[col];
        #pragma unroll
        for (int m = 0; m < 4; m++)
            #pragma unroll
            for (int r = 0; r < 4; r++) {
                int row = rowbase + vm * 64 + m * 16 + hi * 4 + r;
                Cf[(size_t)row * N + col] = acc[m][n][r] + bv;
            }
    }
}

// ---------------- persistent GRU scan v11: r11 + producer-side fragment-major h ----------------
// 256 WGs x 192 threads; rb = wid>>6 (16 batch rows, 4 independent scan groups), cb = wid&63.
// IDENTICAL to r11 (2.92ms validated) except h lives in hsFM (fragment-major):
//   producer: its 16x16 h-block == FM units 32cb..32cb+31 == ONE contiguous 512B region ->
//             one coherent 8B store/lane, fully coalesced (r11: 16 rows x 8B scattered).
//   stage:    src = hsFM + t*64K + rb*16K + v*8 (v = it*192+tid) -> consecutive lanes read
//             consecutive 16B: 128B-line coalesced (r11: 16B units at 2048B stride, the
//             diagnosed ~524K transactions/step). LDS dest linear (G21-safe).
//   consume:  byte-identical to r11's measured ~0-conflict pattern (kb*1024 + lane*16).
// Transpose happens at the producer (T-repack already had it) -- the only place all three
// constraints (coalesced global, linear LDS dest, conflict-free consume) can coexist.
// Sync (r11-validated): split-half flags, cached stage loads, startup buffer_inv,
// producer vmcnt(0) drain -> flag store (no RMW), x-prefetch between flag and poll-A.
__global__ __launch_bounds__(192, 1) void gru_scan(
        const unsigned short* __restrict__ Whc,   // [3][H][H]
        const unsigned short* __restrict__ Wxc,   // [3][H][I]
        const unsigned short* __restrict__ xbf,   // [S*B][I]
        unsigned short* __restrict__ hsFM,        // [S+1][4 rb][2048 units][8]
        const float* __restrict__ bias2,          // [2H]
        const float* __restrict__ bxh,
        const float* __restrict__ bhh,
        unsigned int* flags) {                    // [4][64] per-WG step flags
    __shared__ __align__(16) char lds[134656];
    const int tid = threadIdx.x;
    const int wid = blockIdx.x;
    const int rb = wid >> 6;          // 0..3
    const int cb = wid & 63;
    const int g = tid / 64;
    const int lane = tid & 63, lo = lane & 15, hi = lane >> 4;
    const int col = cb * 16 + lo;
    char* whl = lds + g * 32768;                         // this wave's 32 wh frags
    char* hstage = lds + 98304;                          // 32 KB fragment-major h tile
    f32x4* Px = (f32x4*)(lds + 131072);                  // 3 KB exchange
    unsigned short* T = (unsigned short*)(lds + 134144); // 512 B store-repack

    // ---- stage wh slices into LDS (once) ----
    {
        const unsigned short* ph = Whc + ((size_t)g * HID + col) * HID + hi * 8;
        #pragma unroll
        for (int kb = 0; kb < 32; kb++)
            __builtin_amdgcn_global_load_lds(
                (const __attribute__((address_space(1))) unsigned int*)(ph + kb * 32),
                (__attribute__((address_space(3))) unsigned int*)(whl + kb * 1024 + lane * 16), 16, 0, 0);
    }
    __syncthreads();
    asm volatile("buffer_inv sc0 sc1" ::: "memory");   // kill pre-launch hsFM L2 lines

    const float bzv  = bias2[col];
    const float brv  = bias2[HID + col];
    const float bxhv = bxh[col];
    const float bhhv = bhh[col];
    float hst[4] = {0.f, 0.f, 0.f, 0.f};   // fp32 state: row = rb*16 + hi*4 + r, col
    const unsigned short* wxp = Wxc + ((size_t)g * HID + col) * INF + hi * 8;
    const unsigned int* flA = flags + rb * 64 + (lane & 31);        // half-A producers (cb<32)
    const unsigned int* flB = flags + rb * 64 + 32 + (lane & 31);   // half-B producers

    // x-side preacts for t=0
    f32x4 ax = {0,0,0,0};
    {
        const unsigned short* xp = xbf + ((size_t)(rb * 16 + lo)) * INF + hi * 8;
        #pragma unroll
        for (int kb = 0; kb < 16; kb++)
            ax = __builtin_amdgcn_mfma_f32_16x16x32_bf16(ld_bf8(xp + kb * 32), ld_bf8(wxp + kb * 32), ax, 0, 0, 0);
    }

    for (int t = 0; t < SEQL; t++) {
        // --- stage h[t] from FM layout: coalesced, cached (poll-A at prev iter end) ---
        if (t > 0) {
            const unsigned short* hf = hsFM + (size_t)t * 65536 + rb * 16384;
            #pragma unroll
            for (int it = 0; it < 6; it++) {            // half A: units 0..1023 (k < 512)
                int v = it * 192 + tid;
                if (v < 1024)
                    __builtin_amdgcn_global_load_lds(
                        (const __attribute__((address_space(1))) unsigned int*)(hf + v * 8),
                        (__attribute__((address_space(3))) unsigned int*)(hstage + v * 16), 16, 0, 0);
            }
            // --- poll half-B producers; A-loads land under this RTT ---
            {
                unsigned int tgt = (unsigned int)t;
                while (!__all(__hip_atomic_load(flB, __ATOMIC_RELAXED, __HIP_MEMORY_SCOPE_AGENT) >= tgt))
                    __builtin_amdgcn_s_sleep(1);
                asm volatile("" ::: "memory");
            }
            #pragma unroll
            for (int it = 0; it < 6; it++) {            // half B: units 1024..2047
                int v = 1024 + it * 192 + tid;
                if (v < 2048)
                    __builtin_amdgcn_global_load_lds(
                        (const __attribute__((address_space(1))) unsigned int*)(hf + v * 8),
                        (__attribute__((address_space(3))) unsigned int*)(hstage + v * 16), 16, 0, 0);
            }
        }
        __syncthreads();   // stage landed (per-thread vmcnt drained at barrier)

        // --- h-side preacts: conflict-free lane-linear LDS reads (r11-identical) ---
        f32x4 ah = {0,0,0,0};
        if (t > 0) {
            #pragma unroll
            for (int kb = 0; kb < 32; kb++) {
                bf16x8 w = ld_bf8(whl + kb * 1024 + lane * 16);
                bf16x8 a = ld_bf8(hstage + kb * 1024 + lane * 16);
                ah = __builtin_amdgcn_mfma_f32_16x16x32_bf16(a, w, ah, 0, 0, 0);
            }
        }

        // --- exchange r-pre and both hcand parts via LDS ---
        if (g == 1) {
            f32x4 v;
            #pragma unroll
            for (int r = 0; r < 4; r++) v[r] = ah[r] + ax[r] + brv;
            Px[0 * 64 + lane] = v;
        } else if (g == 2) {
            f32x4 v, w;
            #pragma unroll
            for (int r = 0; r < 4; r++) { v[r] = ah[r] + bhhv; w[r] = ax[r] + bxhv; }
            Px[1 * 64 + lane] = v;
            Px[2 * 64 + lane] = w;
        }
        __syncthreads();

        // --- finalize by wave 0: gates -> new h -> T-repack -> ONE contiguous 8B store/lane ---
        if (g == 0) {
            f32x4 pr = Px[0 * 64 + lane];
            f32x4 ph_ = Px[1 * 64 + lane];
            f32x4 px_ = Px[2 * 64 + lane];
            #pragma unroll
            for (int r = 0; r < 4; r++) {
                float z  = 1.f / (1.f + __expf(-(ah[r] + ax[r] + bzv)));
                float rr = 1.f / (1.f + __expf(-pr[r]));
                float hc = tanhf(px_[r] + rr * ph_[r]);
                hst[r] = (1.f - z) * hst[r] + z * hc;
                T[(hi * 4 + r) * 16 + lo] = f2bf(hst[r]);   // T[row16][col16]
            }
            asm volatile("s_waitcnt lgkmcnt(0)" ::: "memory");  // cross-lane T writes complete
            // FM store: block = units 32cb..32cb+31 (contiguous 512B); lane l -> 8B half-unit.
            unsigned short* fmdst = hsFM + (size_t)(t + 1) * 65536 + rb * 16384 + cb * 256;
            st_u64c(fmdst + lane * 4,
                    *(const unsigned long long*)(T + ((lane >> 1) & 15) * 16 + (lane >> 5) * 8 + (lane & 1) * 4));
            asm volatile("s_waitcnt vmcnt(0)" ::: "memory");    // h-store at the IF
        }
        if (tid == 0)
            __hip_atomic_store(flags + rb * 64 + cb, (unsigned int)(t + 1),
                               __ATOMIC_RELAXED, __HIP_MEMORY_SCOPE_AGENT);

        // --- x-prefetch for t+1 (L2-warm) overlaps flag propagation; then poll half A ---
        f32x4 nax = {0,0,0,0};
        if (t + 1 < SEQL) {
            const unsigned short* xp = xbf + ((size_t)(t + 1) * BATCH + rb * 16 + lo) * INF + hi * 8;
            #pragma unroll
            for (int kb = 0; kb < 16; kb++)
                nax = __builtin_amdgcn_mfma_f32_16x16x32_bf16(ld_bf8(xp + kb * 32), ld_bf8(wxp + kb * 32), nax, 0, 0, 0);
            unsigned int tgt = (unsigned int)(t + 1);
            while (!__all(__hip_atomic_load(flA, __ATOMIC_RELAXED, __HIP_MEMORY_SCOPE_AGENT) >= tgt))
                __builtin_amdgcn_s_sleep(1);
            asm volatile("" ::: "memory");   // pin next iter's half-A stage behind the poll
        }
        ax = nax;
    }
}

// ---------------- host ----------------
extern "C" void kernel_launch(void* const* d_in, const int* in_sizes, int n_in,
                              void* d_out, int out_size, void* d_ws, size_t ws_size,
                              hipStream_t stream) {
    const float* x   = (const float*)d_in[0];
    const float* Wxz = (const float*)d_in[1];
    const float* bxz = (const float*)d_in[2];
    const float* Whz = (const float*)d_in[3];
    const float* bhz = (const float*)d_in[4];
    const float* Wxr = (const float*)d_in[5];
    const float* bxr = (const float*)d_in[6];
    const float* Whr = (const float*)d_in[7];
    const float* bhr = (const float*)d_in[8];
    const float* Wxh = (const float*)d_in[9];
    const float* bxh = (const float*)d_in[10];
    const float* Whh = (const float*)d_in[11];
    const float* bhh = (const float*)d_in[12];
    const float* Why = (const float*)d_in[13];
    const float* bhy = (const float*)d_in[14];

    char* ws = (char*)d_ws;
    size_t off = 0;
    auto alloc = [&](size_t bytes) { char* p = ws + off; off += (bytes + 255) & ~(size_t)255; return p; };
    unsigned short* Whc   = (unsigned short*)alloc((size_t)3 * HID * HID * 2);
    unsigned short* Wxc   = (unsigned short*)alloc((size_t)3 * HID * INF * 2);
    unsigned short* Whyb  = (unsigned short*)alloc((size_t)OUTF * HID * 2);
    float*          bias2 = (float*)alloc((size_t)2 * HID * 4);
    unsigned short* hsFM  = (unsigned short*)alloc((size_t)(SEQL + 1) * 65536 * 2); // 65.7 MB FM h
    unsigned int*   flags = (unsigned int*)alloc(1024);
    unsigned short* x_bf  = (unsigned short*)d_out;  // dead until the final GEMM

    if (off > ws_size) {
        fail_sentinel<<<dim3(1), dim3(1), 0, stream>>>((float*)d_out);
        return;
    }

    auto cvt = [&](const float* s, unsigned short* d, size_t n) {
        cvt_f32_bf16<<<dim3((unsigned)((n / 4 + 255) / 256)), dim3(256), 0, stream>>>(s, d, (int)n);
    };
    cvt(x, x_bf, (size_t)SB * INF);
    cvt(Whz, Whc, (size_t)HID * HID);
    cvt(Whr, Whc + (size_t)HID * HID, (size_t)HID * HID);
    cvt(Whh, Whc + (size_t)2 * HID * HID, (size_t)HID * HID);
    cvt(Wxz, Wxc, (size_t)HID * INF);
    cvt(Wxr, Wxc + (size_t)HID * INF, (size_t)HID * INF);
    cvt(Wxh, Wxc + (size_t)2 * HID * INF, (size_t)HID * INF);
    cvt(Why, Whyb, (size_t)OUTF * HID);
    make_bias2<<<dim3(8), dim3(256), 0, stream>>>(bxz, bhz, bxr, bhr, bias2);
    (void)hipMemsetAsync(flags, 0, 1024, stream);   // reset per launch (graph-replay safe)

    gru_scan<<<dim3(256), dim3(192), 0, stream>>>(Whc, Wxc, x_bf, hsFM, bias2, bxh, bhh, flags);

    // out[SB, O] = hs[1..512] @ Why^T + bhy ; A read from FM layout (t=1 block onward)
    gemm_nt_f32<<<dim3((SB / 128) * (OUTF / 128)), dim3(256), 0, stream>>>(
        hsFM + 65536, Whyb, HID, bhy, (float*)d_out, OUTF, HID);
}